// Round 3
// baseline (665.822 us; speedup 1.0000x reference)
//
#include <hip/hip_runtime.h>
#include <hip/hip_bf16.h>

#define NC     80
#define BATCH  1048576
#define CHUNKS (BATCH / 32)          // 32768 K-chunks of 32 rows
#define NBLK   1024
#define NTHR   256
#define NWAVES (NBLK * NTHR / 64)    // 4096 waves, 8 chunks/wave
#define NTILE  15                    // upper-triangle 16x16 tiles of 80x80

using bf16x8 = __attribute__((ext_vector_type(8))) __bf16;
using f32x4  = __attribute__((ext_vector_type(4))) float;

// G = label^T @ label (upper-triangle 16x16 tiles) via bf16 MFMA, then the
// LAST block to finish computes the smooth-L1 loss against pre_adj.
//
// Session ledger:
//  R0 (509.8us): v[8][5] staging, shift/or pack, global-atomic epilogue. BEST.
//  R1 (528.7us): partial-buffer + reduce pass  -> REGRESSED. Atomics are cheap.
//  R2 (527.5us): pairwise loads + launch_bounds(,4) -> REGRESSED. The 128-VGPR
//     cap forces per-pair vmcnt drains (4 serialized HBM latencies/chunk);
//     R0's 40-loads-in-flight staging is the right shape. Occupancy phases
//     don't matter: kernel is HBM-saturated even at 1 block/CU.
//  R3: restore R0 main loop EXACTLY; fuse loss via last-block pattern
//     (release fence + agent-scope counter + agent-scope G loads).
//
// Exactness: labels are {0,1} -> bf16 truncation exact; all partial sums are
// integers < 2^24 -> fp32 atomicAdd accumulation exact & order-independent.
__global__ __launch_bounds__(NTHR) void gram_loss_kernel(const float* __restrict__ label,
                                                         const float* __restrict__ pre_adj,
                                                         float* __restrict__ G,
                                                         int* __restrict__ cnt,
                                                         float* __restrict__ out) {
    __shared__ float Gs[NC * NC];
    const int tid = threadIdx.x;
    for (int u = tid; u < NC * NC; u += NTHR) Gs[u] = 0.0f;

    const int lane = tid & 63;
    const int m    = lane & 15;   // class-within-tile (output col / frag row)
    const int quad = lane >> 4;   // k-subchunk selector

    const int wid = (blockIdx.x * NTHR + tid) >> 6;   // global wave id

    f32x4 acc[NTILE];
#pragma unroll
    for (int t = 0; t < NTILE; ++t) acc[t] = (f32x4){0.f, 0.f, 0.f, 0.f};

    for (int c = wid; c < CHUNKS; c += NWAVES) {
        // lane reads 8 fp32 per fragment: rows kbase+quad*8+j, col 16t+m.
        // Rows are 320 B = 5 aligned 64B lines; each line fetched exactly once.
        // All 40 loads independent & in flight together (latency hiding).
        const float* base = label + (size_t)(c * 32 + quad * 8) * NC + m;
        float v[8][5];
#pragma unroll
        for (int j = 0; j < 8; ++j) {
            const float* rp = base + j * NC;
#pragma unroll
            for (int t = 0; t < 5; ++t) v[j][t] = rp[t * 16];
        }

        // fp32 -> bf16 by top-16-bit truncation (exact for 0.0 / 1.0)
        bf16x8 frag[5];
#pragma unroll
        for (int t = 0; t < 5; ++t) {
            union { unsigned int u[4]; bf16x8 b; } cv;
#pragma unroll
            for (int p = 0; p < 4; ++p) {
                unsigned lo = __float_as_uint(v[2 * p][t]) >> 16;
                unsigned hi = __float_as_uint(v[2 * p + 1][t]) & 0xFFFF0000u;
                cv.u[p] = hi | lo;
            }
            frag[t] = cv.b;
        }

        // G tile (ti,tj) = frag[ti]-as-A x frag[tj]-as-B ; upper triangle only
        int idx = 0;
#pragma unroll
        for (int ti = 0; ti < 5; ++ti)
#pragma unroll
            for (int tj = ti; tj < 5; ++tj) {
                acc[idx] = __builtin_amdgcn_mfma_f32_16x16x32_bf16(
                    frag[ti], frag[tj], acc[idx], 0, 0, 0);
                ++idx;
            }
    }

    __syncthreads();   // Gs zero-init complete across all waves

    // wave accs -> LDS (C/D layout: col = lane&15, row = quad*4 + reg)
    {
        int idx = 0;
#pragma unroll
        for (int ti = 0; ti < 5; ++ti)
#pragma unroll
            for (int tj = ti; tj < 5; ++tj) {
#pragma unroll
                for (int r = 0; r < 4; ++r) {
                    int row = 16 * ti + quad * 4 + r;
                    int col = 16 * tj + m;
                    atomicAdd(&Gs[row * NC + col], acc[idx][r]);
                }
                ++idx;
            }
    }
    __syncthreads();

    // block partial -> global (upper-triangle tiles only; 15 atomics/thread).
    // Measured R1: cheaper than any partial-buffer + reduce alternative.
    {
        int r  = tid >> 4;
        int cl = tid & 15;
#pragma unroll
        for (int ti = 0; ti < 5; ++ti)
#pragma unroll
            for (int tj = ti; tj < 5; ++tj) {
                int row = 16 * ti + r, col = 16 * tj + cl;
                atomicAdd(&G[row * NC + col], Gs[row * NC + col]);
            }
    }

    // ---- last-block loss fusion ----------------------------------------
    __threadfence();       // release this thread's G atomics (device scope)
    __syncthreads();       // all threads of the block fenced
    __shared__ int is_last;
    if (tid == 0) {
        int old = __hip_atomic_fetch_add(cnt, 1, __ATOMIC_ACQ_REL,
                                         __HIP_MEMORY_SCOPE_AGENT);
        is_last = (old == NBLK - 1);
    }
    __syncthreads();
    if (!is_last) return;

    // Last block: G is final. Read via agent-scope atomic loads (per-XCD L2s
    // are not coherent; these bypass to the coherent point).
    float sum = 0.f;
    for (int u = tid; u < NC * NC; u += NTHR) {
        int i = u / NC, j = u - i * NC;
        float target;
        if (i == j) {
            target = 1.0f;
        } else {
            // G stored only for tile(i) <= tile(j); G is symmetric
            int a = (i >> 4) <= (j >> 4) ? i * NC + j : j * NC + i;
            float num = __hip_atomic_load(&G[a], __ATOMIC_RELAXED,
                                          __HIP_MEMORY_SCOPE_AGENT);
            float cn  = __hip_atomic_load(&G[i * NC + i], __ATOMIC_RELAXED,
                                          __HIP_MEMORY_SCOPE_AGENT);
            target = num / (cn + 1e-7f);
        }
        float r = fabsf(pre_adj[u] - target);
        sum += (r < 1.0f) ? r * r : (r - 0.5f);
    }
#pragma unroll
    for (int off = 32; off > 0; off >>= 1) sum += __shfl_down(sum, off);
    __shared__ float ws[4];
    if ((tid & 63) == 0) ws[tid >> 6] = sum;
    __syncthreads();
    if (tid == 0) out[0] = (ws[0] + ws[1] + ws[2] + ws[3]) * (1.0f / 6400.0f);
}

extern "C" void kernel_launch(void* const* d_in, const int* in_sizes, int n_in,
                              void* d_out, int out_size, void* d_ws, size_t ws_size,
                              hipStream_t stream) {
    const float* pre_adj = (const float*)d_in[0];   // [80,80]
    const float* label   = (const float*)d_in[1];   // [1048576,80]
    float* out = (float*)d_out;                     // scalar
    float* G   = (float*)d_ws;                      // 80*80 fp32 accumulator
    int*   cnt = (int*)(G + NC * NC);               // completion counter

    // zero G + counter (workspace arrives poisoned each iteration)
    hipMemsetAsync(G, 0, (NC * NC + 1) * sizeof(float), stream);
    gram_loss_kernel<<<NBLK, NTHR, 0, stream>>>(label, pre_adj, G, cnt, out);
}

// Round 4
// 508.807 us; speedup vs baseline: 1.3086x; 1.3086x over previous
//
#include <hip/hip_runtime.h>
#include <hip/hip_bf16.h>

#define NC     80
#define BATCH  1048576
#define CHUNKS (BATCH / 32)          // 32768 K-chunks of 32 rows
#define NBLK   1024
#define NTHR   256
#define NWAVES (NBLK * NTHR / 64)    // 4096 waves, 8 chunks/wave

using bf16x8 = __attribute__((ext_vector_type(8))) __bf16;
using f32x4  = __attribute__((ext_vector_type(4))) float;

// Stage 1: G = label^T @ label (upper-triangle 16x16 tiles), bf16 MFMA.
// Labels are exactly {0,1} -> bf16 truncation is exact; all partial sums are
// integers < 2^24 -> fp32 atomicAdd accumulation is exact & order-independent.
//
// Session ledger (DO NOT "improve" this kernel without reading):
//  R0 (509.8us): THIS exact configuration. BEST.
//  R1 (528.7us): partial-buffer + reduce pass   -> REGRESSED (atomics are cheap).
//  R2 (527.5us): pairwise loads + bounds(,4)    -> REGRESSED (reg cap serialized
//                 the staging loads).
//  R3 (665.8us): last-block loss fusion         -> REGRESSED BADLY. Counters:
//                 VGPR fell to 72, kernel went latency-bound (6% HBM, 360us).
//                 The 40-load staging NEEDS ~120+ live VGPRs; the loss tail
//                 changed the allocator's choice and chopped the pipeline.
//  R4: exact revert to R0. The structure below is a measured local optimum;
//      its register allocation (all 40 staging loads in flight) is the key
//      property. Total wall time is ~82% harness poison fills (2 x ~206us),
//      gram ~90us vs ~53us streaming floor, loss+memset+gaps ~10us.
__global__ __launch_bounds__(NTHR) void gram_kernel(const float* __restrict__ label,
                                                    float* __restrict__ G) {
    __shared__ float Gs[NC * NC];
    const int tid = threadIdx.x;
    for (int u = tid; u < NC * NC; u += NTHR) Gs[u] = 0.0f;

    const int lane = tid & 63;
    const int m    = lane & 15;   // class-within-tile (output col / frag row)
    const int quad = lane >> 4;   // k-subchunk selector

    const int wid = (blockIdx.x * NTHR + tid) >> 6;   // global wave id

    f32x4 acc[15];
#pragma unroll
    for (int t = 0; t < 15; ++t) acc[t] = (f32x4){0.f, 0.f, 0.f, 0.f};

    for (int c = wid; c < CHUNKS; c += NWAVES) {
        // lane reads 8 fp32 per fragment: rows kbase+quad*8+j, col 16t+m.
        // Rows are 320 B = 5 aligned 64B lines; each line fetched exactly once.
        // All 40 loads are independent and stay in flight together.
        const float* base = label + (size_t)(c * 32 + quad * 8) * NC + m;
        float v[8][5];
#pragma unroll
        for (int j = 0; j < 8; ++j) {
            const float* rp = base + j * NC;
#pragma unroll
            for (int t = 0; t < 5; ++t) v[j][t] = rp[t * 16];
        }

        // fp32 -> bf16 by top-16-bit truncation (exact for 0.0 / 1.0)
        bf16x8 frag[5];
#pragma unroll
        for (int t = 0; t < 5; ++t) {
            union { unsigned int u[4]; bf16x8 b; } cv;
#pragma unroll
            for (int p = 0; p < 4; ++p) {
                unsigned lo = __float_as_uint(v[2 * p][t]) >> 16;
                unsigned hi = __float_as_uint(v[2 * p + 1][t]) & 0xFFFF0000u;
                cv.u[p] = hi | lo;
            }
            frag[t] = cv.b;
        }

        // G tile (ti,tj) = frag[ti]^T-as-A x frag[tj]-as-B ; upper triangle only
        int idx = 0;
#pragma unroll
        for (int ti = 0; ti < 5; ++ti)
#pragma unroll
            for (int tj = ti; tj < 5; ++tj) {
                acc[idx] = __builtin_amdgcn_mfma_f32_16x16x32_bf16(
                    frag[ti], frag[tj], acc[idx], 0, 0, 0);
                ++idx;
            }
    }

    __syncthreads();   // Gs zero-init complete across all waves

    // wave accs -> LDS (C/D layout: col = lane&15, row = quad*4 + reg)
    {
        int idx = 0;
#pragma unroll
        for (int ti = 0; ti < 5; ++ti)
#pragma unroll
            for (int tj = ti; tj < 5; ++tj) {
#pragma unroll
                for (int r = 0; r < 4; ++r) {
                    int row = 16 * ti + quad * 4 + r;
                    int col = 16 * tj + m;
                    atomicAdd(&Gs[row * NC + col], acc[idx][r]);
                }
                ++idx;
            }
    }
    __syncthreads();

    // block partial -> global (upper-triangle tiles only; 15 atomics/thread)
    {
        int r  = tid >> 4;
        int cl = tid & 15;
#pragma unroll
        for (int ti = 0; ti < 5; ++ti)
#pragma unroll
            for (int tj = ti; tj < 5; ++tj) {
                int row = 16 * ti + r, col = 16 * tj + cl;
                atomicAdd(&G[row * NC + col], Gs[row * NC + col]);
            }
    }
}

// Stage 2: target = cooc/(count+eps) + eye ; smooth-L1-ish ; mean -> out[0]
__global__ __launch_bounds__(256) void loss_kernel(const float* __restrict__ pre_adj,
                                                   const float* __restrict__ G,
                                                   float* __restrict__ out) {
    const int tid = threadIdx.x;
    float sum = 0.f;
    for (int u = tid; u < NC * NC; u += 256) {
        int i = u / NC, j = u - i * NC;
        float target;
        if (i == j) {
            target = 1.0f;
        } else {
            // G stored only for tile(i) <= tile(j); G is symmetric
            float num = ((i >> 4) <= (j >> 4)) ? G[i * NC + j] : G[j * NC + i];
            float cnt = G[i * NC + i];            // count[i] = diag (binary labels)
            target = num / (cnt + 1e-7f);
        }
        float r = fabsf(pre_adj[u] - target);
        sum += (r < 1.0f) ? r * r : (r - 0.5f);
    }
    // wave reduce (64 lanes) then cross-wave via LDS
#pragma unroll
    for (int off = 32; off > 0; off >>= 1) sum += __shfl_down(sum, off);
    __shared__ float ws[4];
    if ((tid & 63) == 0) ws[tid >> 6] = sum;
    __syncthreads();
    if (tid == 0) out[0] = (ws[0] + ws[1] + ws[2] + ws[3]) * (1.0f / 6400.0f);
}

extern "C" void kernel_launch(void* const* d_in, const int* in_sizes, int n_in,
                              void* d_out, int out_size, void* d_ws, size_t ws_size,
                              hipStream_t stream) {
    const float* pre_adj = (const float*)d_in[0];   // [80,80]
    const float* label   = (const float*)d_in[1];   // [1048576,80]
    float* out = (float*)d_out;                     // scalar
    float* G   = (float*)d_ws;                      // 80*80 fp32 accumulator

    hipMemsetAsync(G, 0, NC * NC * sizeof(float), stream);
    gram_kernel<<<NBLK, NTHR, 0, stream>>>(label, G);
    loss_kernel<<<1, 256, 0, stream>>>(pre_adj, G, out);
}

// Round 5
// 478.965 us; speedup vs baseline: 1.3901x; 1.0623x over previous
//
#include <hip/hip_runtime.h>
#include <hip/hip_bf16.h>

#define NC     80
#define BATCH  1048576
#define CHUNKS (BATCH / 32)          // 32768 K-chunks of 32 rows (10240 B each, contiguous)
#define NBLK   512
#define NTHR   128                   // 2 waves/block
#define NWAVES (NBLK * NTHR / 64)    // 1024 waves -> 32 chunks/wave, exact cover
#define NTILE  15                    // upper-triangle 16x16 tiles of 80x80
#define CHUNK_BYTES 10240
#define CHUNK_FLOATS 2560

using bf16x8 = __attribute__((ext_vector_type(8))) __bf16;
using f32x4  = __attribute__((ext_vector_type(4))) float;

// Session ledger:
//  R0/R4 (508.8us): v[8][5] register staging. gram ~200us (inferred from
//     R3-R4 subtraction: overhead const ~305us). Only explanation consistent
//     with all models: allocator spills the 40 staging floats to scratch
//     (R3 measured VGPR=72 for this loop!) -> 3-4x effective traffic.
//  R1 (528.7us): partial-buffer + reduce  -> REGRESSED (atomics are cheap).
//  R2 (527.5us): pairwise + bounds(,4)    -> REGRESSED (serialized loads).
//  R3 (665.8us): loss fusion              -> REGRESSED (VGPR 72, spill hell).
//  R5 (this): staging via global_load_lds DMA -- no VGPRs involved in
//     staging at all; spill impossible by construction. Per-wave double
//     buffer, counted vmcnt(10) waits (never drain in-loop), 10 contiguous
//     dwordx4 wave-loads per chunk. LDS 56320 B/block (<64K static).

#define WAITV10 asm volatile("s_waitcnt vmcnt(10)" ::: "memory")
#define WAITV0  asm volatile("s_waitcnt vmcnt(0)"  ::: "memory")
#define WAITLG  asm volatile("s_waitcnt lgkmcnt(0)" ::: "memory")

__device__ __forceinline__ void gload16(const void* g, void* l) {
    // direct global->LDS DMA, 16 B/lane; LDS dest = uniform base + lane*16
    __builtin_amdgcn_global_load_lds(
        (__attribute__((address_space(1))) void*)g,
        (__attribute__((address_space(3))) void*)l,
        16, 0, 0);
}

// issue 10 wave-loads covering one contiguous 10240 B chunk
__device__ __forceinline__ void stage_chunk(const float* __restrict__ label,
                                            int cidx, float* lbuf, int lane) {
    const char* g = (const char*)label + (size_t)cidx * CHUNK_BYTES + lane * 16;
#pragma unroll
    for (int w = 0; w < 10; ++w)
        gload16(g + w * 1024, lbuf + w * 256);
}

// build 5 bf16 fragments from the LDS chunk and do the 15 upper-tri MFMAs.
// lane reads L[(quad*8+j)*80 + t*16 + m]  (same data/frag order as R0 -> exact)
__device__ __forceinline__ void compute_chunk(const float* L, f32x4* acc,
                                              int quad, int m) {
    const float* base = L + quad * 8 * NC + m;
    bf16x8 frag[5];
#pragma unroll
    for (int t = 0; t < 5; ++t) {
        union { unsigned int u[4]; bf16x8 b; } cv;
#pragma unroll
        for (int p = 0; p < 4; ++p) {
            // fp32 -> bf16 by top-16-bit truncation (exact for 0.0 / 1.0)
            unsigned lo = __float_as_uint(base[(2 * p) * NC + t * 16]) >> 16;
            unsigned hi = __float_as_uint(base[(2 * p + 1) * NC + t * 16]) & 0xFFFF0000u;
            cv.u[p] = hi | lo;
        }
        frag[t] = cv.b;
    }
    int idx = 0;
#pragma unroll
    for (int ti = 0; ti < 5; ++ti)
#pragma unroll
        for (int tj = ti; tj < 5; ++tj) {
            acc[idx] = __builtin_amdgcn_mfma_f32_16x16x32_bf16(
                frag[ti], frag[tj], acc[idx], 0, 0, 0);
            ++idx;
        }
}

__global__ __launch_bounds__(NTHR) void gram_kernel(const float* __restrict__ label,
                                                    float* __restrict__ G) {
    // compact Gs: only the 15 upper-triangle tiles, tile-major
    __shared__ float Gs[NTILE * 256];
    __shared__ float stage[2][2][CHUNK_FLOATS];   // [wave][buf][floats]

    const int tid  = threadIdx.x;
    const int lane = tid & 63;
    const int wv   = tid >> 6;               // wave within block (0..1)
    const int m    = lane & 15;              // class-within-tile
    const int quad = lane >> 4;              // k-subchunk selector
    const int wid  = blockIdx.x * 2 + wv;    // global wave id (0..1023)

    float* b0 = &stage[wv][0][0];
    float* b1 = &stage[wv][1][0];

    // prologue: two chunks in flight before anything else
    stage_chunk(label, wid, b0, lane);
    stage_chunk(label, wid + NWAVES, b1, lane);

    // Gs zero-init overlaps the DMA latency
    for (int u = tid; u < NTILE * 256; u += NTHR) Gs[u] = 0.0f;

    f32x4 acc[NTILE];
#pragma unroll
    for (int t = 0; t < NTILE; ++t) acc[t] = (f32x4){0.f, 0.f, 0.f, 0.f};

    // 32 chunks/wave; steady state keeps 10-20 loads outstanding (never 0)
    const int n = CHUNKS / NWAVES;           // 32
    for (int i = 0; i < n - 2; i += 2) {
        WAITV10;                             // chunk i landed; i+1 in flight
        compute_chunk(b0, acc, quad, m);
        WAITLG;                              // ds_reads done before overwrite
        stage_chunk(label, wid + (i + 2) * NWAVES, b0, lane);

        WAITV10;                             // chunk i+1 landed; i+2 in flight
        compute_chunk(b1, acc, quad, m);
        WAITLG;
        stage_chunk(label, wid + (i + 3) * NWAVES, b1, lane);
    }
    WAITV10;                                 // chunk n-2 landed
    compute_chunk(b0, acc, quad, m);
    WAITV0;                                  // chunk n-1 landed
    compute_chunk(b1, acc, quad, m);

    __syncthreads();   // Gs zero-init + all waves' K-loops complete

    // wave accs -> LDS (C/D layout: col = lane&15, row = quad*4 + reg)
    {
        int idx = 0;
#pragma unroll
        for (int ti = 0; ti < 5; ++ti)
#pragma unroll
            for (int tj = ti; tj < 5; ++tj) {
#pragma unroll
                for (int r = 0; r < 4; ++r)
                    atomicAdd(&Gs[idx * 256 + (quad * 4 + r) * 16 + m], acc[idx][r]);
                ++idx;
            }
    }
    __syncthreads();

    // block partial -> global (R1 lesson: direct atomics beat partial buffers)
    {
        static const unsigned char TI[NTILE] = {0,0,0,0,0,1,1,1,1,2,2,2,3,3,4};
        static const unsigned char TJ[NTILE] = {0,1,2,3,4,1,2,3,4,2,3,4,3,4,4};
#pragma unroll
        for (int idx = 0; idx < NTILE; ++idx) {
            for (int e = tid; e < 256; e += NTHR) {
                int row = 16 * TI[idx] + (e >> 4);
                int col = 16 * TJ[idx] + (e & 15);
                atomicAdd(&G[row * NC + col], Gs[idx * 256 + e]);
            }
        }
    }
}

// Stage 2: target = cooc/(count+eps) + eye ; smooth-L1-ish ; mean -> out[0]
__global__ __launch_bounds__(256) void loss_kernel(const float* __restrict__ pre_adj,
                                                   const float* __restrict__ G,
                                                   float* __restrict__ out) {
    const int tid = threadIdx.x;
    float sum = 0.f;
    for (int u = tid; u < NC * NC; u += 256) {
        int i = u / NC, j = u - i * NC;
        float target;
        if (i == j) {
            target = 1.0f;
        } else {
            // G stored only for tile(i) <= tile(j); G is symmetric
            float num = ((i >> 4) <= (j >> 4)) ? G[i * NC + j] : G[j * NC + i];
            float cnt = G[i * NC + i];            // count[i] = diag (binary labels)
            target = num / (cnt + 1e-7f);
        }
        float r = fabsf(pre_adj[u] - target);
        sum += (r < 1.0f) ? r * r : (r - 0.5f);
    }
    // wave reduce (64 lanes) then cross-wave via LDS
#pragma unroll
    for (int off = 32; off > 0; off >>= 1) sum += __shfl_down(sum, off);
    __shared__ float ws[4];
    if ((tid & 63) == 0) ws[tid >> 6] = sum;
    __syncthreads();
    if (tid == 0) out[0] = (ws[0] + ws[1] + ws[2] + ws[3]) * (1.0f / 6400.0f);
}

extern "C" void kernel_launch(void* const* d_in, const int* in_sizes, int n_in,
                              void* d_out, int out_size, void* d_ws, size_t ws_size,
                              hipStream_t stream) {
    const float* pre_adj = (const float*)d_in[0];   // [80,80]
    const float* label   = (const float*)d_in[1];   // [1048576,80]
    float* out = (float*)d_out;                     // scalar
    float* G   = (float*)d_ws;                      // 80*80 fp32 accumulator

    hipMemsetAsync(G, 0, NC * NC * sizeof(float), stream);
    gram_kernel<<<NBLK, NTHR, 0, stream>>>(label, G);
    loss_kernel<<<1, 256, 0, stream>>>(pre_adj, G, out);
}